// Round 2
// baseline (707.229 us; speedup 1.0000x reference)
//
#include <hip/hip_runtime.h>

#define Bn 8
#define Cn 64
#define Fn 256
#define Tn 512
#define FT (Fn*Tn)          // 131072
#define NPIX (Bn*Fn*Tn)     // 1048576
#define NTOT (Bn*Cn*Fn*Tn)  // 67108864

// ws float offsets
#define WS_MT    0               // [B*C*T] SUM over F (atomic, memset to 0)
#define WS_MF    262144          // [B*C*F] SUM over T
#define WS_ZT    393216          // [B][T][C] sigmoid (TRANSPOSED)
#define WS_ZFW   655360          // [B][F][C] sigmoid * wc[c] (TRANSPOSED)
#define WS_P     786432          // [64][24] prefix sums of wc2 (P[k][L])
#define WS_THR   787968          // [32]
#define WS_AHI   788000          // 8192 bf16 (as 4096 floats): A hi plane, frag-linear
#define WS_ALO   792096          // 8192 bf16: A lo plane
#define WS_PSH   796192          // [64 shards][128] partial sums (zeroed in k2)
#define WS_SCALE 804384          // [64] (unused, layout stability)
#define WS_SHIFT 804448          // [64]

typedef __attribute__((ext_vector_type(8))) short bf16x8;
typedef __attribute__((ext_vector_type(4))) float f32x4;

__device__ __forceinline__ void split2(float x, unsigned short& h, unsigned short& l) {
    unsigned u = __builtin_bit_cast(unsigned, x);
    unsigned r = u + 0x7FFFu + ((u >> 16) & 1u);
    h = (unsigned short)(r >> 16);
    float hf = __builtin_bit_cast(float, r & 0xFFFF0000u);
    float lo = x - hf;
    unsigned ul = __builtin_bit_cast(unsigned, lo);
    unsigned rl = ul + 0x7FFFu + ((ul >> 16) & 1u);
    l = (unsigned short)(rl >> 16);
}

// packed f32x2 -> bf16x2 (elem0 -> low 16, elem1 -> high 16)
__device__ __forceinline__ unsigned pk2(float a, float b) {
    unsigned r;
    asm("v_cvt_pk_bf16_f32 %0, %1, %2" : "=v"(r) : "v"(a), "v"(b));
    return r;
}

// ---------------- K1: fused row/col sums, 8 F-chunks per slab ----------------
__global__ __launch_bounds__(256) void k1_sums(const float* __restrict__ x,
                                               float* __restrict__ ws) {
    const int bx = blockIdx.x;                   // 4096 blocks
    const int slab = bx >> 3, chunk = bx & 7;    // slab = b*64+c
    const int wave = threadIdx.x >> 6, lane = threadIdx.x & 63;
    const float4* x4 = (const float4*)x + (size_t)slab * (FT / 4) + chunk * 32 * 128;
    __shared__ float lcs[4 * 512];
    float4 cs0 = {0.f,0.f,0.f,0.f}, cs1 = {0.f,0.f,0.f,0.f};
    #pragma unroll
    for (int r = 0; r < 8; ++r) {
        const int row = wave * 8 + r;            // 0..31 within chunk
        float4 v0 = x4[row * 128 + lane];
        float4 v1 = x4[row * 128 + 64 + lane];
        cs0.x += v0.x; cs0.y += v0.y; cs0.z += v0.z; cs0.w += v0.w;
        cs1.x += v1.x; cs1.y += v1.y; cs1.z += v1.z; cs1.w += v1.w;
        float rs = (v0.x + v0.y) + (v0.z + v0.w) + (v1.x + v1.y) + (v1.z + v1.w);
        #pragma unroll
        for (int m = 1; m < 64; m <<= 1) rs += __shfl_xor(rs, m, 64);
        if (lane == 0) ws[WS_MF + slab * Fn + chunk * 32 + row] = rs;   // SUM over T
    }
    ((float4*)lcs)[wave * 128 + lane] = cs0;
    ((float4*)lcs)[wave * 128 + 64 + lane] = cs1;
    __syncthreads();
    for (int t = threadIdx.x; t < 512; t += 256) {
        float s = lcs[t] + lcs[512 + t] + lcs[1024 + t] + lcs[1536 + t];
        atomicAdd(&ws[WS_MT + slab * Tn + t], s);   // SUM over F
    }
}

// ---------------- K2: channel MLPs + weight split / tables ----------------
__global__ __launch_bounds__(256) void k2_mlp_prep(
    const float* __restrict__ w1, const float* __restrict__ b1,
    const float* __restrict__ w2, const float* __restrict__ b2,
    const float* __restrict__ wc, const float* __restrict__ bc2,
    const float* __restrict__ wo, const float* __restrict__ wc2,
    float* __restrict__ ws) {
    const int blk = blockIdx.x;
    if (blk < 1536) {
        const int wave = threadIdx.x >> 6, c = threadIdx.x & 63;
        const bool is_t = (blk < 1024);
        float m; int b, l;
        if (is_t) {                       // zt positions: p = b*512 + t
            const int p = blk * 4 + wave;
            b = p >> 9; l = p & 511;
            m = ws[WS_MT + (b * 64 + c) * Tn + l] * (1.0f / Fn);
        } else {                          // zf positions: p = b*256 + f
            const int p = (blk - 1024) * 4 + wave;
            b = p >> 8; l = p & 255;
            m = ws[WS_MF + (b * 64 + c) * Fn + l] * (1.0f / Tn);
        }
        float acc = b2[c];
        #pragma unroll
        for (int o = 0; o < 5; ++o) {
            float v = w1[o * 64 + c] * m;
            #pragma unroll
            for (int mm = 1; mm < 64; mm <<= 1) v += __shfl_xor(v, mm, 64);
            const float h = fmaxf(v + b1[o], 0.0f);
            acc = fmaf(w2[c * 5 + o], h, acc);
        }
        const float sg = 1.0f / (1.0f + expf(-acc));
        // TRANSPOSED layouts: contiguous in c -> coalesced writes here, float4 reads in k4
        if (is_t) ws[WS_ZT  + ((b * Tn + l) << 6) + c] = sg;
        else      ws[WS_ZFW + ((b * Fn + l) << 6) + c] = sg * wc[c];
    } else {
        const int tid = threadIdx.x;
        // A (64 x 128) = [Wb | W2], split to bf16 hi/lo, frag-linear layout:
        // chunk = (k>>5)*4 + (m>>4); within: quad=(k>>3)&3, m16=m&15, j=k&7
        unsigned short* AH = (unsigned short*)(ws + WS_AHI);
        unsigned short* AL = (unsigned short*)(ws + WS_ALO);
        for (int i = tid; i < 8192; i += 256) {
            const int chunk = i >> 9, within = i & 511;
            const int quad = within >> 7, m16 = (within >> 3) & 15, j = within & 7;
            const int m = (chunk & 3) * 16 + m16;
            const int k = (chunk >> 2) * 32 + quad * 8 + j;
            float v;
            if (k < 64) v = wo[m * 128 + k] + wo[m * 128 + 64 + k] * bc2[k];
            else        v = wo[m * 128 + k];   // = wo2[m][k-64]
            unsigned short h, l;
            split2(v, h, l);
            AH[i] = h; AL[i] = l;
        }
        // P prefix sums: P[k][L] = sum_{i<L} wc2[k][i]
        for (int c = tid; c < 64; c += 256) {
            float a = 0.f;
            ws[WS_P + c * 24 + 0] = 0.f;
            for (int K = 1; K <= 23; ++K) { a += wc2[c * 23 + K - 1]; ws[WS_P + c * 24 + K] = a; }
        }
        if (tid == 0) {  // exact replication of np.cumsum(np.arange(1,24)/300.0) -> fp32
            double a = 0.0;
            for (int i = 1; i <= 23; ++i) { a += (double)i / 300.0; ws[WS_THR + i - 1] = (float)a; }
            for (int i = 23; i < 32; ++i) ws[WS_THR + i] = 1e30f;
        }
        for (int i = tid; i < 8192; i += 256) ws[WS_PSH + i] = 0.f;   // zero stat shards
    }
}

// ---------------- K4 v3: 2 t-chunks per block, software-pipelined ----------------
// Chunk1's global loads issue before chunk0's MFMA phase (latency hidden).
// Block fixed costs (Pl, zfw, bo, bc) amortized 2x; stats reduced once per block.
#define XSTAGE(XV, ZT)  do {                                                      \
    float amp = 0.f;                                                              \
    _Pragma("unroll")                                                             \
    for (int q = 0; q < 4; ++q) {                                                 \
      amp = fmaf(zf[q].x, ZT[q].x, amp);                                          \
      amp = fmaf(zf[q].y, ZT[q].y, amp);                                          \
      amp = fmaf(zf[q].z, ZT[q].z, amp);                                          \
      amp = fmaf(zf[q].w, ZT[q].w, amp);                                          \
    }                                                                             \
    AmP[kg * 64 + t_local] = amp;                                                 \
    _Pragma("unroll")                                                             \
    for (int g = 0; g < 2; ++g) {                                                 \
      const int k8 = (kg + g * 4) << 3;                                           \
      unsigned ph[4], pl[4];                                                      \
      _Pragma("unroll")                                                           \
      for (int i = 0; i < 4; ++i) {                                               \
        const float x0 = XV[g * 8 + 2 * i], x1 = XV[g * 8 + 2 * i + 1];           \
        const unsigned h = pk2(x0, x1);                                           \
        const float hf0 = __builtin_bit_cast(float, h << 16);                     \
        const float hf1 = __builtin_bit_cast(float, h & 0xFFFF0000u);             \
        ph[i] = h;                                                                \
        pl[i] = pk2(x0 - hf0, x1 - hf1);  /* lo = x - hf: exact */                \
      }                                                                           \
      const int cka = ((k8 >> 5) * 4 + nfrag) * 512 + ((k8 >> 3) & 3) * 128 + n16 * 8; \
      *(int4*)&Bhi[cka] = make_int4(ph[0], ph[1], ph[2], ph[3]);                  \
      *(int4*)&Blo[cka] = make_int4(pl[0], pl[1], pl[2], pl[3]);                  \
    }                                                                             \
  } while (0)

#define GSTAGE(XV)  do {                                                          \
    float am = bc0 + AmP[t_local] + AmP[64 + t_local] + AmP[128 + t_local] + AmP[192 + t_local]; \
    int L = 0;                                                                    \
    _Pragma("unroll")                                                             \
    for (int i = 0; i < 23; ++i) L += (am > wsc[WS_THR + i]) ? 1 : 0;             \
    _Pragma("unroll")                                                             \
    for (int g = 0; g < 2; ++g) {                                                 \
      const int k8 = (kg + g * 4) << 3;                                           \
      unsigned pg[4];                                                             \
      _Pragma("unroll")                                                           \
      for (int i = 0; i < 4; ++i) {                                               \
        const float g0 = am * Pl[(k8 + 2 * i)     * 24 + L] * XV[g * 8 + 2 * i];  \
        const float g1 = am * Pl[(k8 + 2 * i + 1) * 24 + L] * XV[g * 8 + 2 * i + 1]; \
        pg[i] = pk2(g0, g1);                                                      \
      }                                                                           \
      const int cka = ((k8 >> 5) * 4 + nfrag) * 512 + ((k8 >> 3) & 3) * 128 + n16 * 8; \
      *(int4*)&Bhi[cka + 4096] = make_int4(pg[0], pg[1], pg[2], pg[3]);           \
    }                                                                             \
  } while (0)

#define MFMA_EPI(TOFF)  do {                                                      \
    f32x4 acc[4];                                                                 \
    _Pragma("unroll")                                                             \
    for (int nf = 0; nf < 4; ++nf) { acc[nf].x = bo4.x; acc[nf].y = bo4.y; acc[nf].z = bo4.z; acc[nf].w = bo4.w; } \
    _Pragma("unroll")                                                             \
    for (int ks = 0; ks < 4; ++ks) {                                              \
      const int ao = (ks * 4 + w) * 512 + quad * 128 + l16 * 8;                   \
      const bf16x8 ah = *(const bf16x8*)(AH + ao);                                \
      const bf16x8 al = *(const bf16x8*)(AL + ao);                                \
      _Pragma("unroll")                                                           \
      for (int nf = 0; nf < 4; ++nf) {                                            \
        const int bof = (ks * 4 + nf) * 512 + quad * 128 + l16 * 8;               \
        const bf16x8 bh = *(const bf16x8*)&Bhi[bof];                              \
        acc[nf] = __builtin_amdgcn_mfma_f32_16x16x32_bf16(ah, bh, acc[nf], 0, 0, 0); \
        if (ks < 2) {  /* X chunks only: B-lo correction plane */                 \
          const bf16x8 bl = *(const bf16x8*)&Blo[bof];                            \
          acc[nf] = __builtin_amdgcn_mfma_f32_16x16x32_bf16(ah, bl, acc[nf], 0, 0, 0); \
        }                                                                         \
        acc[nf] = __builtin_amdgcn_mfma_f32_16x16x32_bf16(al, bh, acc[nf], 0, 0, 0); \
      }                                                                           \
    }                                                                             \
    float* ob = out + (size_t)b * (Cn * FT) + f * Tn + t0 + (TOFF);               \
    _Pragma("unroll")                                                             \
    for (int r = 0; r < 4; ++r) {                                                 \
      const int c = w * 16 + quad * 4 + r;                                        \
      float vs = 0.f, vq = 0.f;                                                   \
      _Pragma("unroll")                                                           \
      for (int nf = 0; nf < 4; ++nf) {                                            \
        const float v = acc[nf][r];                                               \
        ob[(size_t)c * FT + nf * 16 + l16] = v;                                   \
        vs += v; vq = fmaf(v, v, vq);                                             \
      }                                                                           \
      vsA[r] += vs; vqA[r] += vq;                                                 \
    }                                                                             \
  } while (0)

__global__ __launch_bounds__(256, 4) void k4_main(
    const float* __restrict__ x, const float* __restrict__ wsc,
    const float* __restrict__ bc, const float* __restrict__ bo,
    float* __restrict__ out, float* __restrict__ ws) {
    __shared__ __align__(16) short Bhi[16 * 512];   // 16 KB, frag-linear (X + G)
    __shared__ __align__(16) short Blo[8 * 512];    //  8 KB, X half only
    __shared__ float Pl[64 * 24];                   //  6 KB
    __shared__ float AmP[256];                      //  1 KB
    __shared__ float sstat[128];                    //  0.5 KB   (total 32256 B)

    const int tid = threadIdx.x;
    const int blk = blockIdx.x;                // 8192 blocks
    const int b = blk >> 10;
    const int rem = blk & 1023;
    const int f = rem >> 2;
    const int t0 = (rem & 3) << 7;             // 128-px pair base

    const int t_local = tid & 63, kg = tid >> 6;
    const int nfrag = t_local >> 4, n16 = t_local & 15;
    const int w = kg, quad = nfrag, l16 = n16;

    // ---- prefetch chunk 0 (x strided + zt row) ----
    float xv0[16]; float4 zt0[4];
    {
        const float* xb = x + (size_t)b * (Cn * FT) + f * Tn + t0 + t_local;
        #pragma unroll
        for (int g = 0; g < 2; ++g) {
            const int k8 = (kg + g * 4) << 3;
            #pragma unroll
            for (int i = 0; i < 8; ++i) xv0[g * 8 + i] = xb[(size_t)(k8 + i) * FT];
        }
        const float4* ztp = (const float4*)(wsc + WS_ZT + ((b * Tn + t0 + t_local) << 6)) + kg * 4;
        #pragma unroll
        for (int q = 0; q < 4; ++q) zt0[q] = ztp[q];
    }
    // ---- block invariants ----
    float4 zf[4];
    {
        const float4* zfp = (const float4*)(wsc + WS_ZFW + ((b * Fn + f) << 6)) + kg * 4;
        #pragma unroll
        for (int q = 0; q < 4; ++q) zf[q] = zfp[q];
    }
    for (int i = tid; i < 1536; i += 256) Pl[i] = wsc[WS_P + i];
    const float bc0 = bc[0];
    const float4 bo4 = *(const float4*)&bo[w * 16 + quad * 4];
    const short* AH = (const short*)(wsc + WS_AHI);
    const short* AL = (const short*)(wsc + WS_ALO);
    float vsA[4] = {0.f,0.f,0.f,0.f}, vqA[4] = {0.f,0.f,0.f,0.f};

    // ---- chunk 0 ----
    XSTAGE(xv0, zt0);
    __syncthreads();            // Pl + AmP + X-plane ready
    GSTAGE(xv0);
    __syncthreads();            // G-plane ready
    // prefetch chunk 1 BEFORE the MFMA phase: HBM latency hides under MFMA+stores
    float xv1[16]; float4 zt1[4];
    {
        const float* xb = x + (size_t)b * (Cn * FT) + f * Tn + t0 + 64 + t_local;
        #pragma unroll
        for (int g = 0; g < 2; ++g) {
            const int k8 = (kg + g * 4) << 3;
            #pragma unroll
            for (int i = 0; i < 8; ++i) xv1[g * 8 + i] = xb[(size_t)(k8 + i) * FT];
        }
        const float4* ztp = (const float4*)(wsc + WS_ZT + ((b * Tn + t0 + 64 + t_local) << 6)) + kg * 4;
        #pragma unroll
        for (int q = 0; q < 4; ++q) zt1[q] = ztp[q];
    }
    MFMA_EPI(0);
    __syncthreads();            // LDS reads done, safe to overwrite

    // ---- chunk 1 ----
    XSTAGE(xv1, zt1);
    __syncthreads();
    GSTAGE(xv1);
    __syncthreads();
    MFMA_EPI(64);

    // ---- stats finalize: one reduce + one atomic per block ----
    #pragma unroll
    for (int r = 0; r < 4; ++r) {
        float vs = vsA[r], vq = vqA[r];
        #pragma unroll
        for (int m = 1; m < 16; m <<= 1) { vs += __shfl_xor(vs, m); vq += __shfl_xor(vq, m); }
        if (l16 == 0) { const int c = w * 16 + quad * 4 + r; sstat[c] = vs; sstat[64 + c] = vq; }
    }
    __syncthreads();
    if (tid < 128) atomicAdd(&ws[WS_PSH + (blk & 63) * 128 + tid], sstat[tid]);
}

// ---------------- K7: BN finalize + in-place normalize + ReLU ----------------
__global__ __launch_bounds__(256) void k7_norm(float* __restrict__ o,
                                               const float* __restrict__ gamma,
                                               const float* __restrict__ beta,
                                               const float* __restrict__ ws) {
    __shared__ float ssc[64], ssh[64];
    const int tid = threadIdx.x;
    if (tid < 64) {   // per-block recompute of scale/shift from the 64 shards (L2-resident)
        float s = 0.f, q = 0.f;
        #pragma unroll 8
        for (int sh = 0; sh < 64; ++sh) {
            s += ws[WS_PSH + sh * 128 + tid];
            q += ws[WS_PSH + sh * 128 + 64 + tid];
        }
        const float n = (float)NPIX;
        const float mu = s / n;
        const float var = q / n - mu * mu;
        const float sc = gamma[tid] * rsqrtf(var + 1e-5f);
        ssc[tid] = sc;
        ssh[tid] = beta[tid] - mu * sc;
    }
    __syncthreads();
    const int blk = blockIdx.x;                 // 16384 blocks
    const int slab = blk >> 5, chunk = blk & 31;
    const int c = slab & 63;
    const float sc = ssc[c], sh = ssh[c];
    float4* o4 = (float4*)o + (size_t)slab * (FT / 4) + chunk * 1024;
    #pragma unroll
    for (int i = 0; i < 4; ++i) {
        float4 v = o4[i * 256 + tid];
        v.x = fmaxf(fmaf(v.x, sc, sh), 0.f);
        v.y = fmaxf(fmaf(v.y, sc, sh), 0.f);
        v.z = fmaxf(fmaf(v.z, sc, sh), 0.f);
        v.w = fmaxf(fmaf(v.w, sc, sh), 0.f);
        o4[i * 256 + tid] = v;
    }
}

extern "C" void kernel_launch(void* const* d_in, const int* in_sizes, int n_in,
                              void* d_out, int out_size, void* d_ws, size_t ws_size,
                              hipStream_t stream) {
    const float* x     = (const float*)d_in[0];
    const float* w1    = (const float*)d_in[1];
    const float* b1    = (const float*)d_in[2];
    const float* w2    = (const float*)d_in[3];
    const float* b2    = (const float*)d_in[4];
    const float* wc    = (const float*)d_in[5];
    const float* bc    = (const float*)d_in[6];
    const float* wc2   = (const float*)d_in[7];
    const float* bc2   = (const float*)d_in[8];
    const float* wo    = (const float*)d_in[9];
    const float* bo    = (const float*)d_in[10];
    const float* gamma = (const float*)d_in[11];
    const float* beta  = (const float*)d_in[12];
    float* out = (float*)d_out;
    float* ws  = (float*)d_ws;

    hipMemsetAsync(ws + WS_MT, 0, Bn * Cn * Tn * sizeof(float), stream);  // zero F-sum accumulators
    k1_sums<<<4096, 256, 0, stream>>>(x, ws);
    k2_mlp_prep<<<1537, 256, 0, stream>>>(w1, b1, w2, b2, wc, bc2, wo, wc2, ws);
    k4_main<<<8192, 256, 0, stream>>>(x, ws, bc, bo, out, ws);
    k7_norm<<<16384, 256, 0, stream>>>(out, gamma, beta, ws);
}

// Round 3
// 660.151 us; speedup vs baseline: 1.0713x; 1.0713x over previous
//
#include <hip/hip_runtime.h>

#define Bn 8
#define Cn 64
#define Fn 256
#define Tn 512
#define FT (Fn*Tn)          // 131072
#define NPIX (Bn*Fn*Tn)     // 1048576
#define NTOT (Bn*Cn*Fn*Tn)  // 67108864

// ws float offsets
#define WS_MT    0               // [B*C*T] SUM over F (atomic, memset to 0)
#define WS_MF    262144          // [B*C*F] SUM over T
#define WS_ZT    393216          // [B][T][C] sigmoid (TRANSPOSED)
#define WS_ZFW   655360          // [B][F][C] sigmoid * wc[c] (TRANSPOSED)
#define WS_P     786432          // [64][24] prefix sums of wc2 (P[k][L])
#define WS_THR   787968          // [32]
#define WS_AHI   788000          // 8192 bf16 (as 4096 floats): A hi plane, frag-linear
#define WS_ALO   792096          // 8192 bf16: A lo plane
#define WS_PSH   796192          // [64 shards][128] partial sums (zeroed in k2)
#define WS_O16   805888          // fp16 o-plane: NTOT halves = 33,554,432 floats (ws is 1 GiB)

typedef __attribute__((ext_vector_type(8))) short bf16x8;
typedef __attribute__((ext_vector_type(4))) float f32x4;
typedef __attribute__((ext_vector_type(4))) _Float16 f16x4;

__device__ __forceinline__ void split2(float x, unsigned short& h, unsigned short& l) {
    unsigned u = __builtin_bit_cast(unsigned, x);
    unsigned r = u + 0x7FFFu + ((u >> 16) & 1u);
    h = (unsigned short)(r >> 16);
    float hf = __builtin_bit_cast(float, r & 0xFFFF0000u);
    float lo = x - hf;
    unsigned ul = __builtin_bit_cast(unsigned, lo);
    unsigned rl = ul + 0x7FFFu + ((ul >> 16) & 1u);
    l = (unsigned short)(rl >> 16);
}

// packed f32x2 -> bf16x2 (elem0 -> low 16, elem1 -> high 16), RNE
__device__ __forceinline__ unsigned pk2(float a, float b) {
    unsigned r;
    asm("v_cvt_pk_bf16_f32 %0, %1, %2" : "=v"(r) : "v"(a), "v"(b));
    return r;
}

// ---------------- K1: fused row/col sums, 8 F-chunks per slab ----------------
__global__ __launch_bounds__(256) void k1_sums(const float* __restrict__ x,
                                               float* __restrict__ ws) {
    const int bx = blockIdx.x;                   // 4096 blocks
    const int slab = bx >> 3, chunk = bx & 7;    // slab = b*64+c
    const int wave = threadIdx.x >> 6, lane = threadIdx.x & 63;
    const float4* x4 = (const float4*)x + (size_t)slab * (FT / 4) + chunk * 32 * 128;
    __shared__ float lcs[4 * 512];
    float4 cs0 = {0.f,0.f,0.f,0.f}, cs1 = {0.f,0.f,0.f,0.f};
    #pragma unroll
    for (int r = 0; r < 8; ++r) {
        const int row = wave * 8 + r;            // 0..31 within chunk
        float4 v0 = x4[row * 128 + lane];
        float4 v1 = x4[row * 128 + 64 + lane];
        cs0.x += v0.x; cs0.y += v0.y; cs0.z += v0.z; cs0.w += v0.w;
        cs1.x += v1.x; cs1.y += v1.y; cs1.z += v1.z; cs1.w += v1.w;
        float rs = (v0.x + v0.y) + (v0.z + v0.w) + (v1.x + v1.y) + (v1.z + v1.w);
        #pragma unroll
        for (int m = 1; m < 64; m <<= 1) rs += __shfl_xor(rs, m, 64);
        if (lane == 0) ws[WS_MF + slab * Fn + chunk * 32 + row] = rs;   // SUM over T
    }
    ((float4*)lcs)[wave * 128 + lane] = cs0;
    ((float4*)lcs)[wave * 128 + 64 + lane] = cs1;
    __syncthreads();
    for (int t = threadIdx.x; t < 512; t += 256) {
        float s = lcs[t] + lcs[512 + t] + lcs[1024 + t] + lcs[1536 + t];
        atomicAdd(&ws[WS_MT + slab * Tn + t], s);   // SUM over F
    }
}

// ---------------- K2: channel MLPs + weight split / tables ----------------
__global__ __launch_bounds__(256) void k2_mlp_prep(
    const float* __restrict__ w1, const float* __restrict__ b1,
    const float* __restrict__ w2, const float* __restrict__ b2,
    const float* __restrict__ wc, const float* __restrict__ bc2,
    const float* __restrict__ wo, const float* __restrict__ wc2,
    float* __restrict__ ws) {
    const int blk = blockIdx.x;
    if (blk < 1536) {
        const int wave = threadIdx.x >> 6, c = threadIdx.x & 63;
        const bool is_t = (blk < 1024);
        float m; int b, l;
        if (is_t) {                       // zt positions: p = b*512 + t
            const int p = blk * 4 + wave;
            b = p >> 9; l = p & 511;
            m = ws[WS_MT + (b * 64 + c) * Tn + l] * (1.0f / Fn);
        } else {                          // zf positions: p = b*256 + f
            const int p = (blk - 1024) * 4 + wave;
            b = p >> 8; l = p & 255;
            m = ws[WS_MF + (b * 64 + c) * Fn + l] * (1.0f / Tn);
        }
        float acc = b2[c];
        #pragma unroll
        for (int o = 0; o < 5; ++o) {
            float v = w1[o * 64 + c] * m;
            #pragma unroll
            for (int mm = 1; mm < 64; mm <<= 1) v += __shfl_xor(v, mm, 64);
            const float h = fmaxf(v + b1[o], 0.0f);
            acc = fmaf(w2[c * 5 + o], h, acc);
        }
        const float sg = 1.0f / (1.0f + expf(-acc));
        // TRANSPOSED layouts: contiguous in c -> coalesced writes here, float4 reads in k4
        if (is_t) ws[WS_ZT  + ((b * Tn + l) << 6) + c] = sg;
        else      ws[WS_ZFW + ((b * Fn + l) << 6) + c] = sg * wc[c];
    } else {
        const int tid = threadIdx.x;
        // A (64 x 128) = [Wb | W2], split to bf16 hi/lo, frag-linear layout:
        // chunk = (k>>5)*4 + (m>>4); within: quad=(k>>3)&3, m16=m&15, j=k&7
        unsigned short* AH = (unsigned short*)(ws + WS_AHI);
        unsigned short* AL = (unsigned short*)(ws + WS_ALO);
        for (int i = tid; i < 8192; i += 256) {
            const int chunk = i >> 9, within = i & 511;
            const int quad = within >> 7, m16 = (within >> 3) & 15, j = within & 7;
            const int m = (chunk & 3) * 16 + m16;
            const int k = (chunk >> 2) * 32 + quad * 8 + j;
            float v;
            if (k < 64) v = wo[m * 128 + k] + wo[m * 128 + 64 + k] * bc2[k];
            else        v = wo[m * 128 + k];   // = wo2[m][k-64]
            unsigned short h, l;
            split2(v, h, l);
            AH[i] = h; AL[i] = l;
        }
        // P prefix sums: P[k][L] = sum_{i<L} wc2[k][i]
        for (int c = tid; c < 64; c += 256) {
            float a = 0.f;
            ws[WS_P + c * 24 + 0] = 0.f;
            for (int K = 1; K <= 23; ++K) { a += wc2[c * 23 + K - 1]; ws[WS_P + c * 24 + K] = a; }
        }
        if (tid == 0) {  // exact replication of np.cumsum(np.arange(1,24)/300.0) -> fp32
            double a = 0.0;
            for (int i = 1; i <= 23; ++i) { a += (double)i / 300.0; ws[WS_THR + i - 1] = (float)a; }
            for (int i = 23; i < 32; ++i) ws[WS_THR + i] = 1e30f;
        }
        for (int i = tid; i < 8192; i += 256) ws[WS_PSH + i] = 0.f;   // zero stat shards
    }
}

// ---------------- K4 v4: single-chunk (reverted pipeline), slim LDS, fp16 o-plane ----------------
// LDS 24,064 B -> 6 blocks/CU. B staged bf16-hi only (X-lo term ~6e-4 rms in o, flip-noise
// dominates at 0.03). A keeps hi/lo (precomputed, free). 32 MFMAs. o written fp16 to ws.
__global__ __launch_bounds__(256, 6) void k4_main(
    const float* __restrict__ x, const float* __restrict__ wsc,
    const float* __restrict__ bc, const float* __restrict__ bo,
    float* __restrict__ ws) {
    __shared__ __align__(16) short Bhi[16 * 512];   // 16 KB: chunks 0-7 = X, 8-15 = G
    __shared__ float Pl[64 * 24];                   //  6 KB
    __shared__ float AmP[256];                      //  1 KB
    __shared__ float sstat[128];                    //  0.5 KB  (total 24,064 B)

    const int tid = threadIdx.x;
    const int blk = blockIdx.x;                // 16384 blocks
    const int b = blk >> 11;
    const int rem = blk & 2047;
    const int f = rem >> 3;
    const int t0 = (rem & 7) << 6;

    const int t_local = tid & 63, kg = tid >> 6;
    const int nfrag = t_local >> 4, n16 = t_local & 15;

    // --- x loads first (latency hides under table loads + am) ---
    const float* xb = x + (size_t)b * (Cn * FT) + f * Tn + t0 + t_local;
    float xv[16];
    #pragma unroll
    for (int g = 0; g < 2; ++g) {
        const int k8 = (kg + g * 4) << 3;          // 0,8,...,56
        #pragma unroll
        for (int i = 0; i < 8; ++i) xv[g * 8 + i] = xb[(size_t)(k8 + i) * FT];
    }
    // --- z tables (float4, transposed layout) ---
    float4 zt[4], zf[4];
    {
        const float4* ztp = (const float4*)(wsc + WS_ZT  + ((size_t)(b * Tn + t0 + t_local) << 6)) + kg * 4;
        const float4* zfp = (const float4*)(wsc + WS_ZFW + ((size_t)(b * Fn + f) << 6)) + kg * 4;
        #pragma unroll
        for (int q = 0; q < 4; ++q) { zt[q] = ztp[q]; zf[q] = zfp[q]; }
    }
    for (int i = tid; i < 1536; i += 256) Pl[i] = wsc[WS_P + i];

    // --- cooperative am partial: wave kg covers channels [kg*16, kg*16+16) ---
    float amp = 0.f;
    #pragma unroll
    for (int q = 0; q < 4; ++q) {
        amp = fmaf(zf[q].x, zt[q].x, amp);
        amp = fmaf(zf[q].y, zt[q].y, amp);
        amp = fmaf(zf[q].z, zt[q].z, amp);
        amp = fmaf(zf[q].w, zt[q].w, amp);
    }
    AmP[kg * 64 + t_local] = amp;

    // --- stage X (bf16 hi only) ---
    #pragma unroll
    for (int g = 0; g < 2; ++g) {
        const int k8 = (kg + g * 4) << 3;
        unsigned ph[4];
        #pragma unroll
        for (int i = 0; i < 4; ++i) ph[i] = pk2(xv[g * 8 + 2 * i], xv[g * 8 + 2 * i + 1]);
        const int cka = ((k8 >> 5) * 4 + nfrag) * 512 + ((k8 >> 3) & 3) * 128 + n16 * 8;
        *(int4*)&Bhi[cka] = make_int4(ph[0], ph[1], ph[2], ph[3]);
    }
    __syncthreads();   // Pl + AmP + X-plane ready

    // --- full am + threshold level L ---
    const float am = bc[0] + AmP[t_local] + AmP[64 + t_local] + AmP[128 + t_local] + AmP[192 + t_local];
    int L = 0;
    #pragma unroll
    for (int i = 0; i < 23; ++i) L += (am > wsc[WS_THR + i]) ? 1 : 0;

    // --- stage G (bf16 hi only) ---
    #pragma unroll
    for (int g = 0; g < 2; ++g) {
        const int k8 = (kg + g * 4) << 3;
        unsigned pg[4];
        #pragma unroll
        for (int i = 0; i < 4; ++i) {
            const float g0 = am * Pl[(k8 + 2 * i)     * 24 + L] * xv[g * 8 + 2 * i];
            const float g1 = am * Pl[(k8 + 2 * i + 1) * 24 + L] * xv[g * 8 + 2 * i + 1];
            pg[i] = pk2(g0, g1);
        }
        const int cka = ((k8 >> 5) * 4 + nfrag) * 512 + ((k8 >> 3) & 3) * 128 + n16 * 8;
        *(int4*)&Bhi[cka + 4096] = make_int4(pg[0], pg[1], pg[2], pg[3]);
    }
    __syncthreads();   // G-plane ready

    // --- MFMA: wave w owns channels [w*16, w*16+16); 4 n-frags; K = 128; 32 MFMAs ---
    const int w = kg, quad = nfrag, l16 = n16;
    const short* AH = (const short*)(wsc + WS_AHI);
    const short* AL = (const short*)(wsc + WS_ALO);

    f32x4 acc[4];
    const float4 bo4 = *(const float4*)&bo[w * 16 + quad * 4];
    #pragma unroll
    for (int nf = 0; nf < 4; ++nf) { acc[nf].x = bo4.x; acc[nf].y = bo4.y; acc[nf].z = bo4.z; acc[nf].w = bo4.w; }

    #pragma unroll
    for (int ks = 0; ks < 4; ++ks) {
        const int ao = (ks * 4 + w) * 512 + quad * 128 + l16 * 8;
        const bf16x8 ah = *(const bf16x8*)(AH + ao);
        const bf16x8 al = *(const bf16x8*)(AL + ao);
        #pragma unroll
        for (int nf = 0; nf < 4; ++nf) {
            const int bof = (ks * 4 + nf) * 512 + quad * 128 + l16 * 8;
            const bf16x8 bh = *(const bf16x8*)&Bhi[bof];
            acc[nf] = __builtin_amdgcn_mfma_f32_16x16x32_bf16(ah, bh, acc[nf], 0, 0, 0);
            acc[nf] = __builtin_amdgcn_mfma_f32_16x16x32_bf16(al, bh, acc[nf], 0, 0, 0);
        }
    }

    // --- write o as fp16 to ws + fused BN partial stats (stats from fp32 acc) ---
    _Float16* ob = (_Float16*)(ws + WS_O16) + (size_t)b * (Cn * FT) + f * Tn + t0;
    #pragma unroll
    for (int r = 0; r < 4; ++r) {
        const int c = w * 16 + quad * 4 + r;
        float vs = 0.f, vq = 0.f;
        #pragma unroll
        for (int nf = 0; nf < 4; ++nf) {
            const float v = acc[nf][r];
            ob[(size_t)c * FT + nf * 16 + l16] = (_Float16)v;
            vs += v; vq = fmaf(v, v, vq);
        }
        #pragma unroll
        for (int m = 1; m < 16; m <<= 1) { vs += __shfl_xor(vs, m); vq += __shfl_xor(vq, m); }
        if (l16 == 0) { sstat[c] = vs; sstat[64 + c] = vq; }
    }
    __syncthreads();
    if (tid < 128) atomicAdd(&ws[WS_PSH + (blk & 63) * 128 + tid], sstat[tid]);
}

// ---------------- K7: BN finalize + normalize fp16 -> fp32 out + ReLU ----------------
__global__ __launch_bounds__(256) void k7_norm(float* __restrict__ out,
                                               const float* __restrict__ gamma,
                                               const float* __restrict__ beta,
                                               const float* __restrict__ ws) {
    __shared__ float ssc[64], ssh[64];
    const int tid = threadIdx.x;
    if (tid < 64) {   // per-block recompute of scale/shift from the 64 shards (L2-resident)
        float s = 0.f, q = 0.f;
        #pragma unroll 8
        for (int sh = 0; sh < 64; ++sh) {
            s += ws[WS_PSH + sh * 128 + tid];
            q += ws[WS_PSH + sh * 128 + 64 + tid];
        }
        const float n = (float)NPIX;
        const float mu = s / n;
        const float var = q / n - mu * mu;
        const float sc = gamma[tid] * rsqrtf(var + 1e-5f);
        ssc[tid] = sc;
        ssh[tid] = beta[tid] - mu * sc;
    }
    __syncthreads();
    const int blk = blockIdx.x;                 // 16384 blocks
    const int slab = blk >> 5, chunk = blk & 31;
    const int c = slab & 63;
    const float sc = ssc[c], sh = ssh[c];
    const _Float16* ip = (const _Float16*)(ws + WS_O16) + (size_t)slab * FT + chunk * 4096;
    float4* op = (float4*)(out + (size_t)slab * FT + chunk * 4096);
    #pragma unroll
    for (int i = 0; i < 4; ++i) {
        f16x4 h = *(const f16x4*)(ip + i * 1024 + tid * 4);
        float4 v;
        v.x = fmaxf(fmaf((float)h[0], sc, sh), 0.f);
        v.y = fmaxf(fmaf((float)h[1], sc, sh), 0.f);
        v.z = fmaxf(fmaf((float)h[2], sc, sh), 0.f);
        v.w = fmaxf(fmaf((float)h[3], sc, sh), 0.f);
        op[i * 256 + tid] = v;
    }
}

extern "C" void kernel_launch(void* const* d_in, const int* in_sizes, int n_in,
                              void* d_out, int out_size, void* d_ws, size_t ws_size,
                              hipStream_t stream) {
    const float* x     = (const float*)d_in[0];
    const float* w1    = (const float*)d_in[1];
    const float* b1    = (const float*)d_in[2];
    const float* w2    = (const float*)d_in[3];
    const float* b2    = (const float*)d_in[4];
    const float* wc    = (const float*)d_in[5];
    const float* bc    = (const float*)d_in[6];
    const float* wc2   = (const float*)d_in[7];
    const float* bc2   = (const float*)d_in[8];
    const float* wo    = (const float*)d_in[9];
    const float* bo    = (const float*)d_in[10];
    const float* gamma = (const float*)d_in[11];
    const float* beta  = (const float*)d_in[12];
    float* out = (float*)d_out;
    float* ws  = (float*)d_ws;

    hipMemsetAsync(ws + WS_MT, 0, Bn * Cn * Tn * sizeof(float), stream);  // zero F-sum accumulators
    k1_sums<<<4096, 256, 0, stream>>>(x, ws);
    k2_mlp_prep<<<1537, 256, 0, stream>>>(w1, b1, w2, b2, wc, bc2, wo, wc2, ws);
    k4_main<<<16384, 256, 0, stream>>>(x, ws, bc, bo, ws);
    k7_norm<<<16384, 256, 0, stream>>>(out, gamma, beta, ws);
}